// Round 4
// baseline (571.441 us; speedup 1.0000x reference)
//
#include <hip/hip_runtime.h>
#include <hip/hip_bf16.h>
#include <stdint.h>

#define N_NODES 100000
#define N_EDGES 1600000
#define HID 128
#define OUT_DIM 64
#define N_LAYERS 3
#define CAP 64        // ELL row capacity (slots per node); deg~Poisson(16)
#define CAP_SHIFT 6
#define NBINS 4       // fill passes; shrinks active scatter window for L2 residency

typedef __attribute__((ext_vector_type(8))) short short8;
typedef __attribute__((ext_vector_type(4))) float v4f;
typedef __attribute__((ext_vector_type(4))) unsigned short ushort4v;

__device__ __forceinline__ float bf2f(unsigned int lo16) {
    union { unsigned int i; float f; } v; v.i = lo16 << 16; return v.f;
}
__device__ __forceinline__ unsigned short f2bf(float f) {
    union { float f; unsigned int i; } v; v.f = f;
    unsigned int r = v.i + 0x7fffu + ((v.i >> 16) & 1u);  // RNE
    return (unsigned short)(r >> 16);
}

// ---------------- edge dtype detect (int64 vs int32), one wave -----------
__global__ void detect_kernel(const int* __restrict__ raw, int* __restrict__ flag) {
    int lane = threadIdx.x;                 // 64 lanes
    int v = raw[2 * lane + 1];              // odd dwords = int64 high words
    unsigned long long b = __ballot(v != 0);
    if (lane == 0) *flag = (b == 0ull) ? 1 : 0;
}

// ---------------- cursor init: ELL row base = node*CAP -------------------
__global__ void init_cursor(int* __restrict__ cursor) {
    int i = blockIdx.x * blockDim.x + threadIdx.x;
    if (i < N_NODES) cursor[i] = i << CAP_SHIFT;
}

// ---------------- ELL fill: single atomic pass, dst-range binned ----------
__global__ __launch_bounds__(256) void fill_ell(const int* __restrict__ raw,
                                                const int* __restrict__ flag,
                                                int* __restrict__ cursor,
                                                int* __restrict__ ell,
                                                int lo, int hi) {
    int e = blockIdx.x * blockDim.x + threadIdx.x;
    if (e >= N_EDGES) return;
    int s, d;
    if (*flag) {
        const long long* r = (const long long*)raw;
        d = (int)r[N_EDGES + e];
        if (d < lo || d >= hi) return;
        s = (int)r[e];
    } else {
        d = raw[N_EDGES + e];
        if (d < lo || d >= hi) return;
        s = raw[e];
    }
    int p = atomicAdd(&cursor[d], 1);
    if (p < ((d + 1) << CAP_SHIFT)) ell[p] = s;
}

// ---------------- finalize: deg + inv_deg; pad ELL rows to x16 with -------
// sentinel N_NODES (zeroed row in each h buffer) so the double-buffered
// unroll-8 agg pipeline needs no predication or scalar tail.
__global__ void finalize_deg(const int* __restrict__ cursor, int* __restrict__ deg,
                             float* __restrict__ inv_deg, int* __restrict__ ell) {
    int i = blockIdx.x * blockDim.x + threadIdx.x;
    if (i < N_NODES) {
        int d = cursor[i] - (i << CAP_SHIFT);
        if (d > CAP) d = CAP;
        deg[i] = d;
        inv_deg[i] = 1.0f / (float)(d > 0 ? d : 1);
        int r = (d + 15) & ~15;       // pad-16 for the 2-batch pipeline
        int base = i << CAP_SHIFT;
        for (int p = d; p < r; ++p) ell[base + p] = N_NODES;
    }
}

// ---------------- zero the sentinel row (index N_NODES) of h buffers ------
__global__ void zero_pad_rows(unsigned short* b0, unsigned short* b1,
                              unsigned short* b2) {
    int t = threadIdx.x;           // 192 threads: 3 bufs x 64 dwords
    if (t < 192) {
        unsigned short* bufs[3] = {b0, b1, b2};
        uint32_t* p = (uint32_t*)bufs[t >> 6];
        p[(size_t)N_NODES * 64 + (t & 63)] = 0;
    }
}

// ---------------- weight prep: fp32 -> bf16 transposed -------------------
__global__ void prep_weights(const float* __restrict__ Wl, const float* __restrict__ Wr,
                             const float* __restrict__ fc_w,
                             unsigned short* __restrict__ WlT, unsigned short* __restrict__ WrT,
                             unsigned short* __restrict__ fcT) {
    int idx = blockIdx.x * blockDim.x + threadIdx.x;
    const int WELEMS = N_LAYERS * HID * HID;
    if (idx < WELEMS) {
        int l = idx / (HID * HID);
        int rem = idx - l * HID * HID;
        int k = rem / HID, nn2 = rem - k * HID;
        WlT[l * HID * HID + nn2 * HID + k] = f2bf(Wl[idx]);
        WrT[l * HID * HID + nn2 * HID + k] = f2bf(Wr[idx]);
    } else {
        int j = idx - WELEMS;
        if (j < N_LAYERS * HID * OUT_DIM) {
            int l = j / (HID * OUT_DIM);
            int rem = j - l * HID * OUT_DIM;
            int k = rem / OUT_DIM, o = rem - k * OUT_DIM;
            fcT[l * OUT_DIM * HID + o * HID + k] = f2bf(fc_w[(l * HID + k) * OUT_DIM + o]);
        }
    }
}

__global__ void convert_x(const float* __restrict__ x, unsigned short* __restrict__ xb) {
    int i = blockIdx.x * blockDim.x + threadIdx.x;
    if (i < N_NODES * HID / 4) {
        float4 v = ((const float4*)x)[i];
        ushort4v o;
        o[0] = f2bf(v.x); o[1] = f2bf(v.y); o[2] = f2bf(v.z); o[3] = f2bf(v.w);
        ((ushort4v*)xb)[i] = o;
    }
}

// ---------------- agg helpers -------------------------------------------
__device__ __forceinline__ void gather8(const uint4* __restrict__ hv,
                                        int4 i0, int4 i1, int lane16, uint4 v[8]) {
    v[0] = hv[(size_t)i0.x * 16 + lane16];
    v[1] = hv[(size_t)i0.y * 16 + lane16];
    v[2] = hv[(size_t)i0.z * 16 + lane16];
    v[3] = hv[(size_t)i0.w * 16 + lane16];
    v[4] = hv[(size_t)i1.x * 16 + lane16];
    v[5] = hv[(size_t)i1.y * 16 + lane16];
    v[6] = hv[(size_t)i1.z * 16 + lane16];
    v[7] = hv[(size_t)i1.w * 16 + lane16];
}
__device__ __forceinline__ void accum8(const uint4 v[8], float a[8]) {
#pragma unroll
    for (int u = 0; u < 8; ++u) {
        a[0] += bf2f(v[u].x & 0xffffu); a[1] += bf2f(v[u].x >> 16);
        a[2] += bf2f(v[u].y & 0xffffu); a[3] += bf2f(v[u].y >> 16);
        a[4] += bf2f(v[u].z & 0xffffu); a[5] += bf2f(v[u].z >> 16);
        a[6] += bf2f(v[u].w & 0xffffu); a[7] += bf2f(v[u].w >> 16);
    }
}

// ---------------- mean aggregation: 16 nodes/block, 16 lanes/node ---------
// Double-buffered software pipeline: two 8-row batches (A,B) alternate;
// during every accumulate, the OTHER batch's 8 gathers + the next idx
// int4-pair loads stay in flight (FIFO-friendly issue order keeps the
// compiler's s_waitcnt at vmcnt>0). ELL is x16 sentinel-padded; sentinel
// row N_NODES is zeroed and L1-resident, so extra batches cost ~nothing.
__global__ __launch_bounds__(256) void agg_bf(
    const unsigned short* __restrict__ h, const int* __restrict__ ell,
    const int* __restrict__ deg, const float* __restrict__ inv_deg,
    unsigned short* __restrict__ meanb) {
    int tid = threadIdx.x;
    int grp = tid >> 4;          // node slot in block (0..15)
    int lane16 = tid & 15;       // channel octet
    int node = blockIdx.x * 16 + grp;
    bool valid = node < N_NODES;
    int nd = valid ? node : 0;
    int dg = valid ? deg[nd] : 0;
    int dgp = (dg + 15) & ~15;
    int base = nd << CAP_SHIFT;
    const uint4* hv = (const uint4*)h;
    float a[8];
#pragma unroll
    for (int c = 0; c < 8; ++c) a[c] = 0.f;

    if (dgp) {
        int4 iA0 = *(const int4*)&ell[base + 0];
        int4 iA1 = *(const int4*)&ell[base + 4];
        int4 iB0 = *(const int4*)&ell[base + 8];
        int4 iB1 = *(const int4*)&ell[base + 12];
        uint4 vA[8], vB[8];
        gather8(hv, iA0, iA1, lane16, vA);      // batch 0 in flight
        iA0 = *(const int4*)&ell[base + 16];    // idx batch 2 (may be junk; never gathered if OOB)
        iA1 = *(const int4*)&ell[base + 20];
        gather8(hv, iB0, iB1, lane16, vB);      // batch 1 in flight
        iB0 = *(const int4*)&ell[base + 24];    // idx batch 3
        iB1 = *(const int4*)&ell[base + 28];
        int t = 0;
        while (true) {
            accum8(vA, a);                      // waits only batch-A gathers
            bool more = (t + 16) < dgp;
            if (more) {
                gather8(hv, iA0, iA1, lane16, vA);   // batch t/8+2
                iA0 = *(const int4*)&ell[base + t + 32];
                iA1 = *(const int4*)&ell[base + t + 36];
            }
            accum8(vB, a);                      // waits only batch-B gathers
            if (more) {
                gather8(hv, iB0, iB1, lane16, vB);   // batch t/8+3
                iB0 = *(const int4*)&ell[base + t + 40];
                iB1 = *(const int4*)&ell[base + t + 44];
            }
            t += 16;
            if (!more) break;
        }
    }
    if (valid) {
        float id = inv_deg[nd];
        uint4 o;
        o.x = (uint32_t)f2bf(a[0] * id) | ((uint32_t)f2bf(a[1] * id) << 16);
        o.y = (uint32_t)f2bf(a[2] * id) | ((uint32_t)f2bf(a[3] * id) << 16);
        o.z = (uint32_t)f2bf(a[4] * id) | ((uint32_t)f2bf(a[5] * id) << 16);
        o.w = (uint32_t)f2bf(a[6] * id) | ((uint32_t)f2bf(a[7] * id) << 16);
        *(uint4*)&meanb[(size_t)node * HID + lane16 * 8] = o;
    }
}

// ---------------- layer: H = relu(mean@Wl + h@Wr + b), bf16 MFMA ---------
// 64-node tile (grid 1563 ~ 6 blocks/CU) to attack the HBM-miss-latency
// bound seen at 128-tiles (occ 15%, MfmaUtil 6%). Wave w owns 32 output
// cols x all 64 nodes (acc[2][4]). Per t: 12 independent loads (4 mean
// rows + 4 h rows + 4 weight frags) issue together, then 16 MFMAs -> one
// wait-cluster per t, 8 HBM-critical loads in flight per wave.
__global__ __launch_bounds__(256) void layer_mfma(
    const unsigned short* __restrict__ Am,
    const unsigned short* __restrict__ Ah,
    const unsigned short* __restrict__ WlT,
    const unsigned short* __restrict__ WrT,
    const float* __restrict__ bias,
    unsigned short* __restrict__ Hout, int n) {
    int tid = threadIdx.x;
    int w = tid >> 6, L = tid & 63;
    int q = L >> 4, r16 = L & 15;
    int colbase = w << 5;            // wave owns 32 output cols
    int node0 = blockIdx.x * 64;     // block owns 64 nodes

    v4f acc[2][4];
#pragma unroll
    for (int i = 0; i < 2; ++i)
#pragma unroll
        for (int j = 0; j < 4; ++j)
#pragma unroll
            for (int r = 0; r < 4; ++r) acc[i][j][r] = 0.f;

    int nd[4];
#pragma unroll
    for (int j = 0; j < 4; ++j) {
        int t = node0 + j * 16 + r16;
        nd[j] = t < n ? t : n - 1;
    }

#pragma unroll
    for (int t = 0; t < 4; ++t) {
        int koff = t * 32 + q * 8;
        short8 bm[4], bh[4], al[2], ar[2];
#pragma unroll
        for (int j = 0; j < 4; ++j)
            bm[j] = *(const short8*)&Am[(size_t)nd[j] * HID + koff];
#pragma unroll
        for (int j = 0; j < 4; ++j)
            bh[j] = *(const short8*)&Ah[(size_t)nd[j] * HID + koff];
#pragma unroll
        for (int i = 0; i < 2; ++i) {
            al[i] = *(const short8*)&WlT[(colbase + i * 16 + r16) * HID + koff];
            ar[i] = *(const short8*)&WrT[(colbase + i * 16 + r16) * HID + koff];
        }
#pragma unroll
        for (int i = 0; i < 2; ++i)
#pragma unroll
            for (int j = 0; j < 4; ++j)
                acc[i][j] = __builtin_amdgcn_mfma_f32_16x16x32_bf16(al[i], bm[j], acc[i][j], 0, 0, 0);
#pragma unroll
        for (int i = 0; i < 2; ++i)
#pragma unroll
            for (int j = 0; j < 4; ++j)
                acc[i][j] = __builtin_amdgcn_mfma_f32_16x16x32_bf16(ar[i], bh[j], acc[i][j], 0, 0, 0);
    }

#pragma unroll
    for (int i = 0; i < 2; ++i) {
        int col = colbase + i * 16 + q * 4;
        float4 bv = *(const float4*)&bias[col];
#pragma unroll
        for (int j = 0; j < 4; ++j) {
            int node = node0 + j * 16 + r16;
            if (node < n) {
                float v0 = acc[i][j][0] + bv.x;
                float v1 = acc[i][j][1] + bv.y;
                float v2 = acc[i][j][2] + bv.z;
                float v3 = acc[i][j][3] + bv.w;
                ushort4v o;
                o[0] = f2bf(v0 > 0.f ? v0 : 0.f);
                o[1] = f2bf(v1 > 0.f ? v1 : 0.f);
                o[2] = f2bf(v2 > 0.f ? v2 : 0.f);
                o[3] = f2bf(v3 > 0.f ? v3 : 0.f);
                *(ushort4v*)&Hout[(size_t)node * HID + col] = o;
            }
        }
    }
}

// ---------------- layer 3 + FC fused: H3 never touches HBM ---------------
// Same 64-node tile / acc[2][4] GEMM as layer_mfma; relu'd H3 (bf16) goes
// into a 16 KiB LDS tile [64 rows][16 chunks of 16B], chunk XOR-swizzled
// (slot = chunk ^ (row&7)) so write and read are conflict-free. Then
// out[64x64] = [hA hB H3] @ fcT + fc_b; wave w owns 16 rows (acc2[4]).
__global__ __launch_bounds__(256) void layer3_fc(
    const unsigned short* __restrict__ Am,
    const unsigned short* __restrict__ Ah,
    const unsigned short* __restrict__ WlT,
    const unsigned short* __restrict__ WrT,
    const float* __restrict__ bias,
    const unsigned short* __restrict__ hA,
    const unsigned short* __restrict__ hB,
    const unsigned short* __restrict__ fcT,
    const float* __restrict__ fc_b,
    float* __restrict__ out, int n) {
    __shared__ uint4 sm[64 * 16];   // 16 KiB
    int tid = threadIdx.x;
    int w = tid >> 6, L = tid & 63;
    int q = L >> 4, r16 = L & 15;
    int colbase = w << 5;
    int node0 = blockIdx.x * 64;

    v4f acc[2][4];
#pragma unroll
    for (int i = 0; i < 2; ++i)
#pragma unroll
        for (int j = 0; j < 4; ++j)
#pragma unroll
            for (int r = 0; r < 4; ++r) acc[i][j][r] = 0.f;

    int nd[4];
#pragma unroll
    for (int j = 0; j < 4; ++j) {
        int t = node0 + j * 16 + r16;
        nd[j] = t < n ? t : n - 1;
    }

#pragma unroll
    for (int t = 0; t < 4; ++t) {
        int koff = t * 32 + q * 8;
        short8 bm[4], bh[4], al[2], ar[2];
#pragma unroll
        for (int j = 0; j < 4; ++j)
            bm[j] = *(const short8*)&Am[(size_t)nd[j] * HID + koff];
#pragma unroll
        for (int j = 0; j < 4; ++j)
            bh[j] = *(const short8*)&Ah[(size_t)nd[j] * HID + koff];
#pragma unroll
        for (int i = 0; i < 2; ++i) {
            al[i] = *(const short8*)&WlT[(colbase + i * 16 + r16) * HID + koff];
            ar[i] = *(const short8*)&WrT[(colbase + i * 16 + r16) * HID + koff];
        }
#pragma unroll
        for (int i = 0; i < 2; ++i)
#pragma unroll
            for (int j = 0; j < 4; ++j)
                acc[i][j] = __builtin_amdgcn_mfma_f32_16x16x32_bf16(al[i], bm[j], acc[i][j], 0, 0, 0);
#pragma unroll
        for (int i = 0; i < 2; ++i)
#pragma unroll
            for (int j = 0; j < 4; ++j)
                acc[i][j] = __builtin_amdgcn_mfma_f32_16x16x32_bf16(ar[i], bh[j], acc[i][j], 0, 0, 0);
    }

    // epilogue: relu'd H3 -> LDS (swizzled)
#pragma unroll
    for (int i = 0; i < 2; ++i) {
        int col = colbase + i * 16 + q * 4;
        float4 bv = *(const float4*)&bias[col];
#pragma unroll
        for (int j = 0; j < 4; ++j) {
            int row = j * 16 + r16;
            float v0 = acc[i][j][0] + bv.x;
            float v1 = acc[i][j][1] + bv.y;
            float v2 = acc[i][j][2] + bv.z;
            float v3 = acc[i][j][3] + bv.w;
            uint2 val;
            val.x = (uint32_t)f2bf(v0 > 0.f ? v0 : 0.f) |
                    ((uint32_t)f2bf(v1 > 0.f ? v1 : 0.f) << 16);
            val.y = (uint32_t)f2bf(v2 > 0.f ? v2 : 0.f) |
                    ((uint32_t)f2bf(v3 > 0.f ? v3 : 0.f) << 16);
            int slot = (col >> 3) ^ (row & 7);
            uint2* p2 = (uint2*)&sm[(row << 4) + slot];
            p2[q & 1] = val;   // 8B half-chunk
        }
    }
    __syncthreads();

    // ---- FC: out[64 x 64] = [hA hB H3]@fcT + fc_b; wave w owns 16 rows --
    int rowl = (w << 4) + r16;
    int gnode = node0 + rowl;
    bool vf = gnode < n;
    int ndf = vf ? gnode : n - 1;

    v4f acc2[4];
#pragma unroll
    for (int i = 0; i < 4; ++i) {
        float4 bv = *(const float4*)&fc_b[i * 16 + q * 4];
        acc2[i][0] = bv.x; acc2[i][1] = bv.y;
        acc2[i][2] = bv.z; acc2[i][3] = bv.w;
    }

    const unsigned short* hs01[2] = {hA, hB};
#pragma unroll
    for (int l = 0; l < 3; ++l) {
        const unsigned short* F = fcT + (size_t)l * OUT_DIM * HID;
        short8 bq[4];
        if (l < 2) {
#pragma unroll
            for (int t = 0; t < 4; ++t)
                bq[t] = *(const short8*)&hs01[l][(size_t)ndf * HID + t * 32 + q * 8];
        } else {
#pragma unroll
            for (int t = 0; t < 4; ++t)
                bq[t] = *(const short8*)&sm[(rowl << 4) + ((t * 4 + q) ^ (rowl & 7))];
        }
#pragma unroll
        for (int t = 0; t < 4; ++t) {
            int koff = t * 32 + q * 8;
            short8 afr[4];
#pragma unroll
            for (int i = 0; i < 4; ++i)
                afr[i] = *(const short8*)&F[(i * 16 + r16) * HID + koff];
#pragma unroll
            for (int i = 0; i < 4; ++i)
                acc2[i] = __builtin_amdgcn_mfma_f32_16x16x32_bf16(afr[i], bq[t], acc2[i], 0, 0, 0);
        }
    }

#pragma unroll
    for (int i = 0; i < 4; ++i)
        if (vf)
            *(v4f*)&out[(size_t)ndf * OUT_DIM + i * 16 + q * 4] = acc2[i];
}

extern "C" void kernel_launch(void* const* d_in, const int* in_sizes, int n_in,
                              void* d_out, int out_size, void* d_ws, size_t ws_size,
                              hipStream_t stream) {
    const float* x     = (const float*)d_in[0];
    const int*   edges = (const int*)d_in[1];
    const float* Wl    = (const float*)d_in[2];
    const float* Wr    = (const float*)d_in[3];
    const float* b     = (const float*)d_in[4];
    const float* fc_w  = (const float*)d_in[5];
    const float* fc_b  = (const float*)d_in[6];
    float* out = (float*)d_out;

    char* ws = (char*)d_ws;
    size_t off = 0;
    auto alloc = [&](size_t bytes) {
        void* p = ws + off;
        off = (off + bytes + 255) & ~(size_t)255;
        return p;
    };
    int*   flag    = (int*)alloc(256);
    int*   cursor  = (int*)alloc((size_t)N_NODES * 4);
    int*   deg     = (int*)alloc((size_t)N_NODES * 4);
    float* inv_deg = (float*)alloc((size_t)N_NODES * 4);
    // +64 ints slack: pipeline prefetches idx up to 16 ints past a row
    int*   ell     = (int*)alloc(((size_t)N_NODES * CAP + 64) * 4);
    // +1 row: zeroed sentinel row for padded gathers
    unsigned short* xb    = (unsigned short*)alloc((size_t)(N_NODES + 1) * HID * 2);
    unsigned short* meanb = (unsigned short*)alloc((size_t)N_NODES * HID * 2);
    unsigned short* hA    = (unsigned short*)alloc((size_t)(N_NODES + 1) * HID * 2);
    unsigned short* hB    = (unsigned short*)alloc((size_t)(N_NODES + 1) * HID * 2);
    unsigned short* WlT   = (unsigned short*)alloc((size_t)N_LAYERS * HID * HID * 2);
    unsigned short* WrT   = (unsigned short*)alloc((size_t)N_LAYERS * HID * HID * 2);
    unsigned short* fcT   = (unsigned short*)alloc((size_t)N_LAYERS * OUT_DIM * HID * 2);

    detect_kernel<<<1, 64, 0, stream>>>(edges, flag);
    init_cursor<<<(N_NODES + 255) / 256, 256, 0, stream>>>(cursor);
    for (int p = 0; p < NBINS; ++p) {
        int lo = (int)(((long long)N_NODES * p) / NBINS);
        int hi = (int)(((long long)N_NODES * (p + 1)) / NBINS);
        fill_ell<<<(N_EDGES + 255) / 256, 256, 0, stream>>>(edges, flag, cursor, ell, lo, hi);
    }
    finalize_deg<<<(N_NODES + 255) / 256, 256, 0, stream>>>(cursor, deg, inv_deg, ell);
    zero_pad_rows<<<1, 192, 0, stream>>>(xb, hA, hB);

    prep_weights<<<(N_LAYERS * HID * HID + N_LAYERS * HID * OUT_DIM + 255) / 256, 256, 0, stream>>>(
        Wl, Wr, fc_w, WlT, WrT, fcT);
    convert_x<<<(N_NODES * HID / 4 + 255) / 256, 256, 0, stream>>>(x, xb);

    int ngrid = (N_NODES + 63) / 64;
    int agrid = (N_NODES + 15) / 16;

    agg_bf<<<agrid, 256, 0, stream>>>(xb, ell, deg, inv_deg, meanb);
    layer_mfma<<<ngrid, 256, 0, stream>>>(
        meanb, xb, WlT, WrT, b, hA, N_NODES);

    agg_bf<<<agrid, 256, 0, stream>>>(hA, ell, deg, inv_deg, meanb);
    layer_mfma<<<ngrid, 256, 0, stream>>>(
        meanb, hA, WlT + (size_t)HID * HID, WrT + (size_t)HID * HID, b + HID, hB, N_NODES);

    agg_bf<<<agrid, 256, 0, stream>>>(hB, ell, deg, inv_deg, meanb);
    layer3_fc<<<ngrid, 256, 0, stream>>>(
        meanb, hB, WlT + (size_t)2 * HID * HID, WrT + (size_t)2 * HID * HID, b + 2 * HID,
        hA, hB, fcT, fc_b, out, N_NODES);
}

// Round 5
// 532.566 us; speedup vs baseline: 1.0730x; 1.0730x over previous
//
#include <hip/hip_runtime.h>
#include <hip/hip_bf16.h>
#include <stdint.h>

#define N_NODES 100000
#define N_EDGES 1600000
#define HID 128
#define OUT_DIM 64
#define N_LAYERS 3
#define CAP 64        // ELL row capacity (slots per node); deg~Poisson(16)
#define CAP_SHIFT 6
#define NBINS 4       // fill passes; shrinks active scatter window for L2 residency

typedef __attribute__((ext_vector_type(8))) short short8;
typedef __attribute__((ext_vector_type(4))) float v4f;
typedef __attribute__((ext_vector_type(4))) unsigned short ushort4v;

__device__ __forceinline__ float bf2f(unsigned int lo16) {
    union { unsigned int i; float f; } v; v.i = lo16 << 16; return v.f;
}
__device__ __forceinline__ unsigned short f2bf(float f) {
    union { float f; unsigned int i; } v; v.f = f;
    unsigned int r = v.i + 0x7fffu + ((v.i >> 16) & 1u);  // RNE
    return (unsigned short)(r >> 16);
}

// ---------------- detect (int64 vs int32) + cursor init, one kernel ------
__global__ void detect_init(const int* __restrict__ raw, int* __restrict__ flag,
                            int* __restrict__ cursor) {
    int i = blockIdx.x * blockDim.x + threadIdx.x;
    if (blockIdx.x == 0 && threadIdx.x < 64) {
        int v = raw[2 * threadIdx.x + 1];       // odd dwords = int64 high words
        unsigned long long b = __ballot(v != 0);
        if (threadIdx.x == 0) *flag = (b == 0ull) ? 1 : 0;
    }
    if (i < N_NODES) cursor[i] = i << CAP_SHIFT;
}

// ---------------- ELL fill: single atomic pass, dst-range binned ----------
__global__ __launch_bounds__(256) void fill_ell(const int* __restrict__ raw,
                                                const int* __restrict__ flag,
                                                int* __restrict__ cursor,
                                                int* __restrict__ ell,
                                                int lo, int hi) {
    int e = blockIdx.x * blockDim.x + threadIdx.x;
    if (e >= N_EDGES) return;
    int s, d;
    if (*flag) {
        const long long* r = (const long long*)raw;
        d = (int)r[N_EDGES + e];
        if (d < lo || d >= hi) return;
        s = (int)r[e];
    } else {
        d = raw[N_EDGES + e];
        if (d < lo || d >= hi) return;
        s = raw[e];
    }
    int p = atomicAdd(&cursor[d], 1);
    if (p < ((d + 1) << CAP_SHIFT)) ell[p] = s;
}

// ---------------- finalize: deg + inv_deg; pad ELL rows to x8 with --------
// sentinel N_NODES (zeroed row in each h buffer). Block 0 also zeroes the
// sentinel rows of the three h buffers (merged former zero_pad_rows).
__global__ void finalize_deg(const int* __restrict__ cursor, int* __restrict__ deg,
                             float* __restrict__ inv_deg, int* __restrict__ ell,
                             unsigned short* b0, unsigned short* b1,
                             unsigned short* b2) {
    int i = blockIdx.x * blockDim.x + threadIdx.x;
    if (i < N_NODES) {
        int d = cursor[i] - (i << CAP_SHIFT);
        if (d > CAP) d = CAP;
        deg[i] = d;
        inv_deg[i] = 1.0f / (float)(d > 0 ? d : 1);
        int r = (d + 7) & ~7;
        int base = i << CAP_SHIFT;
        for (int p = d; p < r; ++p) ell[base + p] = N_NODES;
    }
    if (blockIdx.x == 0 && threadIdx.x < 192) {
        int t = threadIdx.x;           // 3 bufs x 64 dwords
        unsigned short* bufs[3] = {b0, b1, b2};
        uint32_t* p = (uint32_t*)bufs[t >> 6];
        p[(size_t)N_NODES * 64 + (t & 63)] = 0;
    }
}

// ---------------- prep: x fp32->bf16 + weights fp32->bf16 transposed -----
#define CONV_N (N_NODES * HID / 4)
__global__ void prep_all(const float* __restrict__ x, unsigned short* __restrict__ xb,
                         const float* __restrict__ Wl, const float* __restrict__ Wr,
                         const float* __restrict__ fc_w,
                         unsigned short* __restrict__ WlT, unsigned short* __restrict__ WrT,
                         unsigned short* __restrict__ fcT) {
    int gidx = blockIdx.x * blockDim.x + threadIdx.x;
    if (gidx < CONV_N) {
        float4 v = ((const float4*)x)[gidx];
        ushort4v o;
        o[0] = f2bf(v.x); o[1] = f2bf(v.y); o[2] = f2bf(v.z); o[3] = f2bf(v.w);
        ((ushort4v*)xb)[gidx] = o;
        return;
    }
    int idx = gidx - CONV_N;
    const int WELEMS = N_LAYERS * HID * HID;
    if (idx < WELEMS) {
        int l = idx / (HID * HID);
        int rem = idx - l * HID * HID;
        int k = rem / HID, nn2 = rem - k * HID;
        WlT[l * HID * HID + nn2 * HID + k] = f2bf(Wl[idx]);
        WrT[l * HID * HID + nn2 * HID + k] = f2bf(Wr[idx]);
    } else {
        int j = idx - WELEMS;
        if (j < N_LAYERS * HID * OUT_DIM) {
            int l = j / (HID * OUT_DIM);
            int rem = j - l * HID * OUT_DIM;
            int k = rem / OUT_DIM, o = rem - k * OUT_DIM;
            fcT[l * OUT_DIM * HID + o * HID + k] = f2bf(fc_w[(l * HID + k) * OUT_DIM + o]);
        }
    }
}

// ---------------- mean aggregation: 16 nodes/block, 16 lanes/node ---------
// R0's verified-fast form (57.4 us, 3.66 TB/s): each 16-lane group owns one
// node; each lane covers 8 channels (16B). One dwordx4 gather covers 4 rows
// (1KB). Accumulation completes within each lane. ELL x8-padded with the
// zeroed sentinel row so the unroll-8 loop needs no predication.
__global__ __launch_bounds__(256) void agg_bf(
    const unsigned short* __restrict__ h, const int* __restrict__ ell,
    const int* __restrict__ deg, const float* __restrict__ inv_deg,
    unsigned short* __restrict__ meanb) {
    int tid = threadIdx.x;
    int grp = tid >> 4;          // node slot in block (0..15)
    int lane16 = tid & 15;       // channel octet
    int node = blockIdx.x * 16 + grp;
    bool valid = node < N_NODES;
    int nd = valid ? node : 0;
    int dg = valid ? deg[nd] : 0;
    int dgp = (dg + 7) & ~7;
    int base = nd << CAP_SHIFT;
    const uint4* hv = (const uint4*)h;   // row = 16 uint4
    float a[8];
#pragma unroll
    for (int c = 0; c < 8; ++c) a[c] = 0.f;

    for (int t = 0; t < dgp; t += 8) {
        int idx[8];
#pragma unroll
        for (int u = 0; u < 8; ++u) idx[u] = ell[base + t + u];
        uint4 v[8];
#pragma unroll
        for (int u = 0; u < 8; ++u) v[u] = hv[(size_t)idx[u] * 16 + lane16];
#pragma unroll
        for (int u = 0; u < 8; ++u) {
            a[0] += bf2f(v[u].x & 0xffffu); a[1] += bf2f(v[u].x >> 16);
            a[2] += bf2f(v[u].y & 0xffffu); a[3] += bf2f(v[u].y >> 16);
            a[4] += bf2f(v[u].z & 0xffffu); a[5] += bf2f(v[u].z >> 16);
            a[6] += bf2f(v[u].w & 0xffffu); a[7] += bf2f(v[u].w >> 16);
        }
    }
    if (valid) {
        float id = inv_deg[nd];
        uint4 o;
        o.x = (uint32_t)f2bf(a[0] * id) | ((uint32_t)f2bf(a[1] * id) << 16);
        o.y = (uint32_t)f2bf(a[2] * id) | ((uint32_t)f2bf(a[3] * id) << 16);
        o.z = (uint32_t)f2bf(a[4] * id) | ((uint32_t)f2bf(a[5] * id) << 16);
        o.w = (uint32_t)f2bf(a[6] * id) | ((uint32_t)f2bf(a[7] * id) << 16);
        *(uint4*)&meanb[(size_t)node * HID + lane16 * 8] = o;
    }
}

// ---------------- layer: H = relu(mean@Wl + h@Wr + b), bf16 MFMA ---------
// R0's verified form (~56 us): 128-node tile, wave owns 64 cols x 64 nodes
// (acc[4][4], 128 MFMA / 64 loads per wave).
__global__ __launch_bounds__(256) void layer_mfma(
    const unsigned short* __restrict__ Am,
    const unsigned short* __restrict__ Ah,
    const unsigned short* __restrict__ WlT,
    const unsigned short* __restrict__ WrT,
    const float* __restrict__ bias,
    unsigned short* __restrict__ Hout, int n) {
    int tid = threadIdx.x;
    int w = tid >> 6, L = tid & 63;
    int q = L >> 4, r16 = L & 15;
    int colbase = (w & 1) * 64;
    int nodebase = (w >> 1) * 64;
    int node0 = blockIdx.x * 128;

    v4f acc[4][4];
#pragma unroll
    for (int i = 0; i < 4; ++i)
#pragma unroll
        for (int j = 0; j < 4; ++j)
#pragma unroll
            for (int r = 0; r < 4; ++r) acc[i][j][r] = 0.f;

    int nd[4];
#pragma unroll
    for (int j = 0; j < 4; ++j) {
        int t = node0 + nodebase + j * 16 + r16;
        nd[j] = t < n ? t : n - 1;
    }

#pragma unroll
    for (int seg = 0; seg < 2; ++seg) {
        const unsigned short* A = seg ? Ah : Am;
        const unsigned short* WT = seg ? WrT : WlT;
#pragma unroll
        for (int t = 0; t < 4; ++t) {
            int koff = t * 32 + q * 8;
            short8 afr[4], bfr[4];
#pragma unroll
            for (int i = 0; i < 4; ++i)
                afr[i] = *(const short8*)&WT[(colbase + i * 16 + r16) * HID + koff];
#pragma unroll
            for (int j = 0; j < 4; ++j)
                bfr[j] = *(const short8*)&A[(size_t)nd[j] * HID + koff];
#pragma unroll
            for (int i = 0; i < 4; ++i)
#pragma unroll
                for (int j = 0; j < 4; ++j)
                    acc[i][j] = __builtin_amdgcn_mfma_f32_16x16x32_bf16(afr[i], bfr[j], acc[i][j], 0, 0, 0);
        }
    }

#pragma unroll
    for (int i = 0; i < 4; ++i) {
        int col = colbase + i * 16 + q * 4;
        float4 bv = *(const float4*)&bias[col];
#pragma unroll
        for (int j = 0; j < 4; ++j) {
            int node = node0 + nodebase + j * 16 + r16;
            if (node < n) {
                float v0 = acc[i][j][0] + bv.x;
                float v1 = acc[i][j][1] + bv.y;
                float v2 = acc[i][j][2] + bv.z;
                float v3 = acc[i][j][3] + bv.w;
                ushort4v o;
                o[0] = f2bf(v0 > 0.f ? v0 : 0.f);
                o[1] = f2bf(v1 > 0.f ? v1 : 0.f);
                o[2] = f2bf(v2 > 0.f ? v2 : 0.f);
                o[3] = f2bf(v3 > 0.f ? v3 : 0.f);
                *(ushort4v*)&Hout[(size_t)node * HID + col] = o;
            }
        }
    }
}

// ---------------- layer 3 + FC fused: H3 never touches HBM ---------------
// R3's verified form (70 us vs 112 us separate): 128-tile GEMM as above;
// relu'd H3 (bf16) into a 32 KiB LDS tile [128 rows][16 chunks of 16B],
// chunk XOR-swizzled (slot = chunk ^ (row&7)) so write and read are
// conflict-free. Then out[128x64] = [hA hB H3] @ fcT + fc_b.
__global__ __launch_bounds__(256) void layer3_fc(
    const unsigned short* __restrict__ Am,
    const unsigned short* __restrict__ Ah,
    const unsigned short* __restrict__ WlT,
    const unsigned short* __restrict__ WrT,
    const float* __restrict__ bias,
    const unsigned short* __restrict__ hA,
    const unsigned short* __restrict__ hB,
    const unsigned short* __restrict__ fcT,
    const float* __restrict__ fc_b,
    float* __restrict__ out, int n) {
    __shared__ uint4 sm[128 * 16];   // 32 KiB
    int tid = threadIdx.x;
    int w = tid >> 6, L = tid & 63;
    int q = L >> 4, r16 = L & 15;
    int colbase = (w & 1) * 64;
    int nodebase = (w >> 1) * 64;
    int node0 = blockIdx.x * 128;

    v4f acc[4][4];
#pragma unroll
    for (int i = 0; i < 4; ++i)
#pragma unroll
        for (int j = 0; j < 4; ++j)
#pragma unroll
            for (int r = 0; r < 4; ++r) acc[i][j][r] = 0.f;

    int nd[4];
#pragma unroll
    for (int j = 0; j < 4; ++j) {
        int t = node0 + nodebase + j * 16 + r16;
        nd[j] = t < n ? t : n - 1;
    }

#pragma unroll
    for (int seg = 0; seg < 2; ++seg) {
        const unsigned short* A = seg ? Ah : Am;
        const unsigned short* WT = seg ? WrT : WlT;
#pragma unroll
        for (int t = 0; t < 4; ++t) {
            int koff = t * 32 + q * 8;
            short8 afr[4], bfr[4];
#pragma unroll
            for (int i = 0; i < 4; ++i)
                afr[i] = *(const short8*)&WT[(colbase + i * 16 + r16) * HID + koff];
#pragma unroll
            for (int j = 0; j < 4; ++j)
                bfr[j] = *(const short8*)&A[(size_t)nd[j] * HID + koff];
#pragma unroll
            for (int i = 0; i < 4; ++i)
#pragma unroll
                for (int j = 0; j < 4; ++j)
                    acc[i][j] = __builtin_amdgcn_mfma_f32_16x16x32_bf16(afr[i], bfr[j], acc[i][j], 0, 0, 0);
        }
    }

    // epilogue: relu'd H3 -> LDS (swizzled)
#pragma unroll
    for (int i = 0; i < 4; ++i) {
        int col = colbase + i * 16 + q * 4;
        float4 bv = *(const float4*)&bias[col];
#pragma unroll
        for (int j = 0; j < 4; ++j) {
            int row = nodebase + j * 16 + r16;
            float v0 = acc[i][j][0] + bv.x;
            float v1 = acc[i][j][1] + bv.y;
            float v2 = acc[i][j][2] + bv.z;
            float v3 = acc[i][j][3] + bv.w;
            uint2 val;
            val.x = (uint32_t)f2bf(v0 > 0.f ? v0 : 0.f) |
                    ((uint32_t)f2bf(v1 > 0.f ? v1 : 0.f) << 16);
            val.y = (uint32_t)f2bf(v2 > 0.f ? v2 : 0.f) |
                    ((uint32_t)f2bf(v3 > 0.f ? v3 : 0.f) << 16);
            int slot = (col >> 3) ^ (row & 7);
            uint2* p2 = (uint2*)&sm[(row << 4) + slot];
            p2[q & 1] = val;   // 8B half-chunk
        }
    }
    __syncthreads();

    // ---- FC: out[128 x 64] = [hA hB H3]@fcT + fc_b; wave w owns 32 rows --
    int nd2[2], gvalid[2];
#pragma unroll
    for (int j = 0; j < 2; ++j) {
        int t = node0 + w * 32 + j * 16 + r16;
        gvalid[j] = t < n;
        nd2[j] = gvalid[j] ? t : n - 1;
    }

    v4f acc2[4][2];
#pragma unroll
    for (int i = 0; i < 4; ++i) {
        float4 bv = *(const float4*)&fc_b[i * 16 + q * 4];
#pragma unroll
        for (int j = 0; j < 2; ++j) {
            acc2[i][j][0] = bv.x; acc2[i][j][1] = bv.y;
            acc2[i][j][2] = bv.z; acc2[i][j][3] = bv.w;
        }
    }

    const unsigned short* hs01[2] = {hA, hB};
#pragma unroll
    for (int l = 0; l < 3; ++l) {
        const unsigned short* F = fcT + (size_t)l * OUT_DIM * HID;
#pragma unroll
        for (int t = 0; t < 4; ++t) {
            int koff = t * 32 + q * 8;
            short8 afr[4], bfr[2];
#pragma unroll
            for (int i = 0; i < 4; ++i)
                afr[i] = *(const short8*)&F[(i * 16 + r16) * HID + koff];
#pragma unroll
            for (int j = 0; j < 2; ++j) {
                if (l < 2) {
                    bfr[j] = *(const short8*)&hs01[l][(size_t)nd2[j] * HID + koff];
                } else {
                    int row = w * 32 + j * 16 + r16;
                    bfr[j] = *(const short8*)&sm[(row << 4) + ((t * 4 + q) ^ (row & 7))];
                }
            }
#pragma unroll
            for (int i = 0; i < 4; ++i)
#pragma unroll
                for (int j = 0; j < 2; ++j)
                    acc2[i][j] = __builtin_amdgcn_mfma_f32_16x16x32_bf16(afr[i], bfr[j], acc2[i][j], 0, 0, 0);
        }
    }

#pragma unroll
    for (int i = 0; i < 4; ++i)
#pragma unroll
        for (int j = 0; j < 2; ++j)
            if (gvalid[j])
                *(v4f*)&out[(size_t)nd2[j] * OUT_DIM + i * 16 + q * 4] = acc2[i][j];
}

extern "C" void kernel_launch(void* const* d_in, const int* in_sizes, int n_in,
                              void* d_out, int out_size, void* d_ws, size_t ws_size,
                              hipStream_t stream) {
    const float* x     = (const float*)d_in[0];
    const int*   edges = (const int*)d_in[1];
    const float* Wl    = (const float*)d_in[2];
    const float* Wr    = (const float*)d_in[3];
    const float* b     = (const float*)d_in[4];
    const float* fc_w  = (const float*)d_in[5];
    const float* fc_b  = (const float*)d_in[6];
    float* out = (float*)d_out;

    char* ws = (char*)d_ws;
    size_t off = 0;
    auto alloc = [&](size_t bytes) {
        void* p = ws + off;
        off = (off + bytes + 255) & ~(size_t)255;
        return p;
    };
    int*   flag    = (int*)alloc(256);
    int*   cursor  = (int*)alloc((size_t)N_NODES * 4);
    int*   deg     = (int*)alloc((size_t)N_NODES * 4);
    float* inv_deg = (float*)alloc((size_t)N_NODES * 4);
    int*   ell     = (int*)alloc(((size_t)N_NODES * CAP + 64) * 4);
    // +1 row: zeroed sentinel row for padded gathers
    unsigned short* xb    = (unsigned short*)alloc((size_t)(N_NODES + 1) * HID * 2);
    unsigned short* meanb = (unsigned short*)alloc((size_t)N_NODES * HID * 2);
    unsigned short* hA    = (unsigned short*)alloc((size_t)(N_NODES + 1) * HID * 2);
    unsigned short* hB    = (unsigned short*)alloc((size_t)(N_NODES + 1) * HID * 2);
    unsigned short* WlT   = (unsigned short*)alloc((size_t)N_LAYERS * HID * HID * 2);
    unsigned short* WrT   = (unsigned short*)alloc((size_t)N_LAYERS * HID * HID * 2);
    unsigned short* fcT   = (unsigned short*)alloc((size_t)N_LAYERS * OUT_DIM * HID * 2);

    detect_init<<<(N_NODES + 255) / 256, 256, 0, stream>>>(edges, flag, cursor);
    for (int p = 0; p < NBINS; ++p) {
        int lo = (int)(((long long)N_NODES * p) / NBINS);
        int hi = (int)(((long long)N_NODES * (p + 1)) / NBINS);
        fill_ell<<<(N_EDGES + 255) / 256, 256, 0, stream>>>(edges, flag, cursor, ell, lo, hi);
    }
    finalize_deg<<<(N_NODES + 255) / 256, 256, 0, stream>>>(cursor, deg, inv_deg, ell, xb, hA, hB);

    const int PREP_TOTAL = CONV_N + N_LAYERS * HID * HID + N_LAYERS * HID * OUT_DIM;
    prep_all<<<(PREP_TOTAL + 255) / 256, 256, 0, stream>>>(x, xb, Wl, Wr, fc_w, WlT, WrT, fcT);

    int ngrid = (N_NODES + 127) / 128;
    int agrid = (N_NODES + 15) / 16;

    agg_bf<<<agrid, 256, 0, stream>>>(xb, ell, deg, inv_deg, meanb);
    layer_mfma<<<ngrid, 256, 0, stream>>>(
        meanb, xb, WlT, WrT, b, hA, N_NODES);

    agg_bf<<<agrid, 256, 0, stream>>>(hA, ell, deg, inv_deg, meanb);
    layer_mfma<<<ngrid, 256, 0, stream>>>(
        meanb, hA, WlT + (size_t)HID * HID, WrT + (size_t)HID * HID, b + HID, hB, N_NODES);

    agg_bf<<<agrid, 256, 0, stream>>>(hB, ell, deg, inv_deg, meanb);
    layer3_fc<<<ngrid, 256, 0, stream>>>(
        meanb, hB, WlT + (size_t)2 * HID * HID, WrT + (size_t)2 * HID * HID, b + 2 * HID,
        hA, hB, fcT, fc_b, out, N_NODES);
}

// Round 6
// 516.830 us; speedup vs baseline: 1.1057x; 1.0304x over previous
//
#include <hip/hip_runtime.h>
#include <hip/hip_bf16.h>
#include <stdint.h>

#define N_NODES 100000
#define N_EDGES 1600000
#define HID 128
#define OUT_DIM 64
#define N_LAYERS 3
#define CAP 64        // ELL row capacity (slots per node); deg~Poisson(16)
#define CAP_SHIFT 6
#define NBINS 4       // fill passes; shrinks active scatter window for L2 residency

typedef __attribute__((ext_vector_type(8))) short short8;
typedef __attribute__((ext_vector_type(4))) float v4f;
typedef __attribute__((ext_vector_type(4))) unsigned short ushort4v;

__device__ __forceinline__ float bf2f(unsigned int lo16) {
    union { unsigned int i; float f; } v; v.i = lo16 << 16; return v.f;
}
__device__ __forceinline__ unsigned short f2bf(float f) {
    union { float f; unsigned int i; } v; v.f = f;
    unsigned int r = v.i + 0x7fffu + ((v.i >> 16) & 1u);  // RNE
    return (unsigned short)(r >> 16);
}

// async global->LDS, 16B per lane; LDS dest = wave-uniform base + lane*16,
// global src is per-lane (rule #21: swizzle goes on the SOURCE + the READ).
__device__ __forceinline__ void stage16(const void* g, void* l) {
    __builtin_amdgcn_global_load_lds(
        (const __attribute__((address_space(1))) unsigned int*)g,
        (__attribute__((address_space(3))) unsigned int*)l, 16, 0, 0);
}

// ---------------- detect (int64 vs int32) + cursor init, one kernel ------
__global__ void detect_init(const int* __restrict__ raw, int* __restrict__ flag,
                            int* __restrict__ cursor) {
    int i = blockIdx.x * blockDim.x + threadIdx.x;
    if (blockIdx.x == 0 && threadIdx.x < 64) {
        int v = raw[2 * threadIdx.x + 1];       // odd dwords = int64 high words
        unsigned long long b = __ballot(v != 0);
        if (threadIdx.x == 0) *flag = (b == 0ull) ? 1 : 0;
    }
    if (i < N_NODES) cursor[i] = i << CAP_SHIFT;
}

// ---------------- ELL fill: single atomic pass, dst-range binned ----------
__global__ __launch_bounds__(256) void fill_ell(const int* __restrict__ raw,
                                                const int* __restrict__ flag,
                                                int* __restrict__ cursor,
                                                int* __restrict__ ell,
                                                int lo, int hi) {
    int e = blockIdx.x * blockDim.x + threadIdx.x;
    if (e >= N_EDGES) return;
    int s, d;
    if (*flag) {
        const long long* r = (const long long*)raw;
        d = (int)r[N_EDGES + e];
        if (d < lo || d >= hi) return;
        s = (int)r[e];
    } else {
        d = raw[N_EDGES + e];
        if (d < lo || d >= hi) return;
        s = raw[e];
    }
    int p = atomicAdd(&cursor[d], 1);
    if (p < ((d + 1) << CAP_SHIFT)) ell[p] = s;
}

// ---------------- finalize: deg + inv_deg; pad ELL rows to x8 with --------
// sentinel N_NODES (zeroed row in each h buffer). Block 0 also zeroes the
// sentinel rows of the three h buffers (merged former zero_pad_rows).
__global__ void finalize_deg(const int* __restrict__ cursor, int* __restrict__ deg,
                             float* __restrict__ inv_deg, int* __restrict__ ell,
                             unsigned short* b0, unsigned short* b1,
                             unsigned short* b2) {
    int i = blockIdx.x * blockDim.x + threadIdx.x;
    if (i < N_NODES) {
        int d = cursor[i] - (i << CAP_SHIFT);
        if (d > CAP) d = CAP;
        deg[i] = d;
        inv_deg[i] = 1.0f / (float)(d > 0 ? d : 1);
        int r = (d + 7) & ~7;
        int base = i << CAP_SHIFT;
        for (int p = d; p < r; ++p) ell[base + p] = N_NODES;
    }
    if (blockIdx.x == 0 && threadIdx.x < 192) {
        int t = threadIdx.x;           // 3 bufs x 64 dwords
        unsigned short* bufs[3] = {b0, b1, b2};
        uint32_t* p = (uint32_t*)bufs[t >> 6];
        p[(size_t)N_NODES * 64 + (t & 63)] = 0;
    }
}

// ---------------- prep: x fp32->bf16 + weights fp32->bf16 transposed -----
#define CONV_N (N_NODES * HID / 4)
__global__ void prep_all(const float* __restrict__ x, unsigned short* __restrict__ xb,
                         const float* __restrict__ Wl, const float* __restrict__ Wr,
                         const float* __restrict__ fc_w,
                         unsigned short* __restrict__ WlT, unsigned short* __restrict__ WrT,
                         unsigned short* __restrict__ fcT) {
    int gidx = blockIdx.x * blockDim.x + threadIdx.x;
    if (gidx < CONV_N) {
        float4 v = ((const float4*)x)[gidx];
        ushort4v o;
        o[0] = f2bf(v.x); o[1] = f2bf(v.y); o[2] = f2bf(v.z); o[3] = f2bf(v.w);
        ((ushort4v*)xb)[gidx] = o;
        return;
    }
    int idx = gidx - CONV_N;
    const int WELEMS = N_LAYERS * HID * HID;
    if (idx < WELEMS) {
        int l = idx / (HID * HID);
        int rem = idx - l * HID * HID;
        int k = rem / HID, nn2 = rem - k * HID;
        WlT[l * HID * HID + nn2 * HID + k] = f2bf(Wl[idx]);
        WrT[l * HID * HID + nn2 * HID + k] = f2bf(Wr[idx]);
    } else {
        int j = idx - WELEMS;
        if (j < N_LAYERS * HID * OUT_DIM) {
            int l = j / (HID * OUT_DIM);
            int rem = j - l * HID * OUT_DIM;
            int k = rem / OUT_DIM, o = rem - k * OUT_DIM;
            fcT[l * OUT_DIM * HID + o * HID + k] = f2bf(fc_w[(l * HID + k) * OUT_DIM + o]);
        }
    }
}

// ---------------- mean aggregation: 16 nodes/block, 16 lanes/node ---------
// R0's verified-fast form (57.4 us, 3.66 TB/s): each 16-lane group owns one
// node; each lane covers 8 channels (16B). One dwordx4 gather covers 4 rows
// (1KB). Accumulation completes within each lane. ELL x8-padded with the
// zeroed sentinel row so the unroll-8 loop needs no predication.
__global__ __launch_bounds__(256) void agg_bf(
    const unsigned short* __restrict__ h, const int* __restrict__ ell,
    const int* __restrict__ deg, const float* __restrict__ inv_deg,
    unsigned short* __restrict__ meanb) {
    int tid = threadIdx.x;
    int grp = tid >> 4;          // node slot in block (0..15)
    int lane16 = tid & 15;       // channel octet
    int node = blockIdx.x * 16 + grp;
    bool valid = node < N_NODES;
    int nd = valid ? node : 0;
    int dg = valid ? deg[nd] : 0;
    int dgp = (dg + 7) & ~7;
    int base = nd << CAP_SHIFT;
    const uint4* hv = (const uint4*)h;   // row = 16 uint4
    float a[8];
#pragma unroll
    for (int c = 0; c < 8; ++c) a[c] = 0.f;

    for (int t = 0; t < dgp; t += 8) {
        int idx[8];
#pragma unroll
        for (int u = 0; u < 8; ++u) idx[u] = ell[base + t + u];
        uint4 v[8];
#pragma unroll
        for (int u = 0; u < 8; ++u) v[u] = hv[(size_t)idx[u] * 16 + lane16];
#pragma unroll
        for (int u = 0; u < 8; ++u) {
            a[0] += bf2f(v[u].x & 0xffffu); a[1] += bf2f(v[u].x >> 16);
            a[2] += bf2f(v[u].y & 0xffffu); a[3] += bf2f(v[u].y >> 16);
            a[4] += bf2f(v[u].z & 0xffffu); a[5] += bf2f(v[u].z >> 16);
            a[6] += bf2f(v[u].w & 0xffffu); a[7] += bf2f(v[u].w >> 16);
        }
    }
    if (valid) {
        float id = inv_deg[nd];
        uint4 o;
        o.x = (uint32_t)f2bf(a[0] * id) | ((uint32_t)f2bf(a[1] * id) << 16);
        o.y = (uint32_t)f2bf(a[2] * id) | ((uint32_t)f2bf(a[3] * id) << 16);
        o.z = (uint32_t)f2bf(a[4] * id) | ((uint32_t)f2bf(a[5] * id) << 16);
        o.w = (uint32_t)f2bf(a[6] * id) | ((uint32_t)f2bf(a[7] * id) << 16);
        *(uint4*)&meanb[(size_t)node * HID + lane16 * 8] = o;
    }
}

// ---------------- layer: H = relu(mean@Wl + h@Wr + b), bf16 MFMA ---------
// LDS-staged rewrite of the R0 form. The block's 128 Am rows + 128 Ah rows
// (32KB each, CONTIGUOUS) are issued as 64 async global_load_lds(16B)
// instructions up front -> every byte in flight at once, ONE vmcnt drain
// (vs 24 serialized 8x16B load-cluster stalls per wave before: occ 14%,
// MfmaUtil 6%, HBM 12% = latency-bound). gload_lds writes linearly, so the
// bank-conflict fix is rule #21: XOR swizzle (chunk ^ (row&7), 16B units)
// applied to the per-lane global SOURCE address and to the LDS READ (the
// exact involution proven ~conflict-free in layer3_fc's sm tile). Weights
// (32 short8) preload into VGPRs before the barrier so their L2 latency
// hides under the staging drain; compute is pure ds_read_b128 + MFMA.
// 64KB LDS -> 2 blocks/CU. Accumulation order identical to R0 form.
__global__ __launch_bounds__(256, 2) void layer_mfma(
    const unsigned short* __restrict__ Am,
    const unsigned short* __restrict__ Ah,
    const unsigned short* __restrict__ WlT,
    const unsigned short* __restrict__ WrT,
    const float* __restrict__ bias,
    unsigned short* __restrict__ Hout, int n) {
    __shared__ uint4 smA[128 * 16];   // 32 KiB: Am tile (swizzled content)
    __shared__ uint4 smB[128 * 16];   // 32 KiB: Ah tile
    int tid = threadIdx.x;
    int w = tid >> 6, L = tid & 63;
    int q = L >> 4, r16 = L & 15;
    int colbase = (w & 1) * 64;
    int nodebase = (w >> 1) * 64;
    int node0 = blockIdx.x * 128;

    // ---- stage both operand tiles: wave w covers KB-chunks w*8..w*8+7 ----
    {
        const unsigned short* srcs[2] = {Am, Ah};
#pragma unroll
        for (int op = 0; op < 2; ++op) {
            const unsigned short* S = srcs[op];
            char* D = (char*)(op ? smB : smA);
#pragma unroll
            for (int i = 0; i < 8; ++i) {
                int c = (w << 3) + i;              // KB index 0..31
                int row_l = (c << 2) + (L >> 4);   // local row 0..127
                int chunk = (L & 15) ^ (row_l & 7);
                const unsigned short* src =
                    S + (((size_t)(node0 + row_l)) << 7) + (chunk << 3);
                stage16(src, D + (c << 10));
            }
        }
    }

    // ---- preload all weight fragments (L2-hot) under the staging drain ---
    short8 wfr[2][4][4];
#pragma unroll
    for (int seg = 0; seg < 2; ++seg) {
        const unsigned short* WT = seg ? WrT : WlT;
#pragma unroll
        for (int t = 0; t < 4; ++t)
#pragma unroll
            for (int i = 0; i < 4; ++i)
                wfr[seg][t][i] =
                    *(const short8*)&WT[(colbase + i * 16 + r16) * HID + t * 32 + q * 8];
    }

    __syncthreads();   // drains vmcnt(0): staged tiles + weights all ready

    v4f acc[4][4];
#pragma unroll
    for (int i = 0; i < 4; ++i)
#pragma unroll
        for (int j = 0; j < 4; ++j)
#pragma unroll
            for (int r = 0; r < 4; ++r) acc[i][j][r] = 0.f;

#pragma unroll
    for (int seg = 0; seg < 2; ++seg) {
        const uint4* SM = seg ? smB : smA;
#pragma unroll
        for (int t = 0; t < 4; ++t) {
            short8 bfr[4];
#pragma unroll
            for (int j = 0; j < 4; ++j) {
                int row = nodebase + j * 16 + r16;
                bfr[j] = *(const short8*)&SM[(row << 4) + ((t * 4 + q) ^ (row & 7))];
            }
#pragma unroll
            for (int i = 0; i < 4; ++i)
#pragma unroll
                for (int j = 0; j < 4; ++j)
                    acc[i][j] = __builtin_amdgcn_mfma_f32_16x16x32_bf16(
                        wfr[seg][t][i], bfr[j], acc[i][j], 0, 0, 0);
        }
    }

#pragma unroll
    for (int i = 0; i < 4; ++i) {
        int col = colbase + i * 16 + q * 4;
        float4 bv = *(const float4*)&bias[col];
#pragma unroll
        for (int j = 0; j < 4; ++j) {
            int node = node0 + nodebase + j * 16 + r16;
            if (node < n) {
                float v0 = acc[i][j][0] + bv.x;
                float v1 = acc[i][j][1] + bv.y;
                float v2 = acc[i][j][2] + bv.z;
                float v3 = acc[i][j][3] + bv.w;
                ushort4v o;
                o[0] = f2bf(v0 > 0.f ? v0 : 0.f);
                o[1] = f2bf(v1 > 0.f ? v1 : 0.f);
                o[2] = f2bf(v2 > 0.f ? v2 : 0.f);
                o[3] = f2bf(v3 > 0.f ? v3 : 0.f);
                *(ushort4v*)&Hout[(size_t)node * HID + col] = o;
            }
        }
    }
}

// ---------------- layer 3 + FC fused: H3 never touches HBM ---------------
// R3's verified form (70 us vs 112 us separate): 128-tile GEMM;
// relu'd H3 (bf16) into a 32 KiB LDS tile [128 rows][16 chunks of 16B],
// chunk XOR-swizzled (slot = chunk ^ (row&7)) so write and read are
// conflict-free. Then out[128x64] = [hA hB H3] @ fcT + fc_b.
// (Unchanged this round: control for the layer_mfma staging experiment.)
__global__ __launch_bounds__(256) void layer3_fc(
    const unsigned short* __restrict__ Am,
    const unsigned short* __restrict__ Ah,
    const unsigned short* __restrict__ WlT,
    const unsigned short* __restrict__ WrT,
    const float* __restrict__ bias,
    const unsigned short* __restrict__ hA,
    const unsigned short* __restrict__ hB,
    const unsigned short* __restrict__ fcT,
    const float* __restrict__ fc_b,
    float* __restrict__ out, int n) {
    __shared__ uint4 sm[128 * 16];   // 32 KiB
    int tid = threadIdx.x;
    int w = tid >> 6, L = tid & 63;
    int q = L >> 4, r16 = L & 15;
    int colbase = (w & 1) * 64;
    int nodebase = (w >> 1) * 64;
    int node0 = blockIdx.x * 128;

    v4f acc[4][4];
#pragma unroll
    for (int i = 0; i < 4; ++i)
#pragma unroll
        for (int j = 0; j < 4; ++j)
#pragma unroll
            for (int r = 0; r < 4; ++r) acc[i][j][r] = 0.f;

    int nd[4];
#pragma unroll
    for (int j = 0; j < 4; ++j) {
        int t = node0 + nodebase + j * 16 + r16;
        nd[j] = t < n ? t : n - 1;
    }

#pragma unroll
    for (int seg = 0; seg < 2; ++seg) {
        const unsigned short* A = seg ? Ah : Am;
        const unsigned short* WT = seg ? WrT : WlT;
#pragma unroll
        for (int t = 0; t < 4; ++t) {
            int koff = t * 32 + q * 8;
            short8 afr[4], bfr[4];
#pragma unroll
            for (int i = 0; i < 4; ++i)
                afr[i] = *(const short8*)&WT[(colbase + i * 16 + r16) * HID + koff];
#pragma unroll
            for (int j = 0; j < 4; ++j)
                bfr[j] = *(const short8*)&A[(size_t)nd[j] * HID + koff];
#pragma unroll
            for (int i = 0; i < 4; ++i)
#pragma unroll
                for (int j = 0; j < 4; ++j)
                    acc[i][j] = __builtin_amdgcn_mfma_f32_16x16x32_bf16(afr[i], bfr[j], acc[i][j], 0, 0, 0);
        }
    }

    // epilogue: relu'd H3 -> LDS (swizzled)
#pragma unroll
    for (int i = 0; i < 4; ++i) {
        int col = colbase + i * 16 + q * 4;
        float4 bv = *(const float4*)&bias[col];
#pragma unroll
        for (int j = 0; j < 4; ++j) {
            int row = nodebase + j * 16 + r16;
            float v0 = acc[i][j][0] + bv.x;
            float v1 = acc[i][j][1] + bv.y;
            float v2 = acc[i][j][2] + bv.z;
            float v3 = acc[i][j][3] + bv.w;
            uint2 val;
            val.x = (uint32_t)f2bf(v0 > 0.f ? v0 : 0.f) |
                    ((uint32_t)f2bf(v1 > 0.f ? v1 : 0.f) << 16);
            val.y = (uint32_t)f2bf(v2 > 0.f ? v2 : 0.f) |
                    ((uint32_t)f2bf(v3 > 0.f ? v3 : 0.f) << 16);
            int slot = (col >> 3) ^ (row & 7);
            uint2* p2 = (uint2*)&sm[(row << 4) + slot];
            p2[q & 1] = val;   // 8B half-chunk
        }
    }
    __syncthreads();

    // ---- FC: out[128 x 64] = [hA hB H3]@fcT + fc_b; wave w owns 32 rows --
    int nd2[2], gvalid[2];
#pragma unroll
    for (int j = 0; j < 2; ++j) {
        int t = node0 + w * 32 + j * 16 + r16;
        gvalid[j] = t < n;
        nd2[j] = gvalid[j] ? t : n - 1;
    }

    v4f acc2[4][2];
#pragma unroll
    for (int i = 0; i < 4; ++i) {
        float4 bv = *(const float4*)&fc_b[i * 16 + q * 4];
#pragma unroll
        for (int j = 0; j < 2; ++j) {
            acc2[i][j][0] = bv.x; acc2[i][j][1] = bv.y;
            acc2[i][j][2] = bv.z; acc2[i][j][3] = bv.w;
        }
    }

    const unsigned short* hs01[2] = {hA, hB};
#pragma unroll
    for (int l = 0; l < 3; ++l) {
        const unsigned short* F = fcT + (size_t)l * OUT_DIM * HID;
#pragma unroll
        for (int t = 0; t < 4; ++t) {
            int koff = t * 32 + q * 8;
            short8 afr[4], bfr[2];
#pragma unroll
            for (int i = 0; i < 4; ++i)
                afr[i] = *(const short8*)&F[(i * 16 + r16) * HID + koff];
#pragma unroll
            for (int j = 0; j < 2; ++j) {
                if (l < 2) {
                    bfr[j] = *(const short8*)&hs01[l][(size_t)nd2[j] * HID + koff];
                } else {
                    int row = w * 32 + j * 16 + r16;
                    bfr[j] = *(const short8*)&sm[(row << 4) + ((t * 4 + q) ^ (row & 7))];
                }
            }
#pragma unroll
            for (int i = 0; i < 4; ++i)
#pragma unroll
                for (int j = 0; j < 2; ++j)
                    acc2[i][j] = __builtin_amdgcn_mfma_f32_16x16x32_bf16(afr[i], bfr[j], acc2[i][j], 0, 0, 0);
        }
    }

#pragma unroll
    for (int i = 0; i < 4; ++i)
#pragma unroll
        for (int j = 0; j < 2; ++j)
            if (gvalid[j])
                *(v4f*)&out[(size_t)nd2[j] * OUT_DIM + i * 16 + q * 4] = acc2[i][j];
}

extern "C" void kernel_launch(void* const* d_in, const int* in_sizes, int n_in,
                              void* d_out, int out_size, void* d_ws, size_t ws_size,
                              hipStream_t stream) {
    const float* x     = (const float*)d_in[0];
    const int*   edges = (const int*)d_in[1];
    const float* Wl    = (const float*)d_in[2];
    const float* Wr    = (const float*)d_in[3];
    const float* b     = (const float*)d_in[4];
    const float* fc_w  = (const float*)d_in[5];
    const float* fc_b  = (const float*)d_in[6];
    float* out = (float*)d_out;

    char* ws = (char*)d_ws;
    size_t off = 0;
    auto alloc = [&](size_t bytes) {
        void* p = ws + off;
        off = (off + bytes + 255) & ~(size_t)255;
        return p;
    };
    int*   flag    = (int*)alloc(256);
    int*   cursor  = (int*)alloc((size_t)N_NODES * 4);
    int*   deg     = (int*)alloc((size_t)N_NODES * 4);
    float* inv_deg = (float*)alloc((size_t)N_NODES * 4);
    int*   ell     = (int*)alloc(((size_t)N_NODES * CAP + 64) * 4);
    // +1 row: zeroed sentinel row for padded gathers. Staged tiles may read
    // up to 96 rows past n; those land in the next ws allocation (garbage
    // data, predicated off at the store) — all within ws bounds.
    unsigned short* xb    = (unsigned short*)alloc((size_t)(N_NODES + 1) * HID * 2);
    unsigned short* meanb = (unsigned short*)alloc((size_t)(N_NODES + 128) * HID * 2);
    unsigned short* hA    = (unsigned short*)alloc((size_t)(N_NODES + 1) * HID * 2);
    unsigned short* hB    = (unsigned short*)alloc((size_t)(N_NODES + 1) * HID * 2);
    unsigned short* WlT   = (unsigned short*)alloc((size_t)N_LAYERS * HID * HID * 2);
    unsigned short* WrT   = (unsigned short*)alloc((size_t)N_LAYERS * HID * HID * 2);
    unsigned short* fcT   = (unsigned short*)alloc((size_t)N_LAYERS * OUT_DIM * HID * 2);

    detect_init<<<(N_NODES + 255) / 256, 256, 0, stream>>>(edges, flag, cursor);
    for (int p = 0; p < NBINS; ++p) {
        int lo = (int)(((long long)N_NODES * p) / NBINS);
        int hi = (int)(((long long)N_NODES * (p + 1)) / NBINS);
        fill_ell<<<(N_EDGES + 255) / 256, 256, 0, stream>>>(edges, flag, cursor, ell, lo, hi);
    }
    finalize_deg<<<(N_NODES + 255) / 256, 256, 0, stream>>>(cursor, deg, inv_deg, ell, xb, hA, hB);

    const int PREP_TOTAL = CONV_N + N_LAYERS * HID * HID + N_LAYERS * HID * OUT_DIM;
    prep_all<<<(PREP_TOTAL + 255) / 256, 256, 0, stream>>>(x, xb, Wl, Wr, fc_w, WlT, WrT, fcT);

    int ngrid = (N_NODES + 127) / 128;
    int agrid = (N_NODES + 15) / 16;

    agg_bf<<<agrid, 256, 0, stream>>>(xb, ell, deg, inv_deg, meanb);
    layer_mfma<<<ngrid, 256, 0, stream>>>(
        meanb, xb, WlT, WrT, b, hA, N_NODES);

    agg_bf<<<agrid, 256, 0, stream>>>(hA, ell, deg, inv_deg, meanb);
    layer_mfma<<<ngrid, 256, 0, stream>>>(
        meanb, hA, WlT + (size_t)HID * HID, WrT + (size_t)HID * HID, b + HID, hB, N_NODES);

    agg_bf<<<agrid, 256, 0, stream>>>(hB, ell, deg, inv_deg, meanb);
    layer3_fc<<<ngrid, 256, 0, stream>>>(
        meanb, hB, WlT + (size_t)2 * HID * HID, WrT + (size_t)2 * HID * HID, b + 2 * HID,
        hA, hB, fcT, fc_b, out, N_NODES);
}